// Round 9
// baseline (127.056 us; speedup 1.0000x reference)
//
#include <hip/hip_runtime.h>
#include <hip/hip_bf16.h>

#define BATCH 262144
#define NSITES 64
#define NJ 4                    // j-tiles per wave (64 batch elems/wave)
#define BLOCK_BATCH 256         // batch elems per 256-thread block
#define SS 4                    // steps per superstep

typedef __attribute__((ext_vector_type(8))) short short8;
typedef __attribute__((ext_vector_type(4))) float f32x4;

__device__ __forceinline__ unsigned cvt_pk_bf16(float a, float b) {
  unsigned r;
  asm("v_cvt_pk_bf16_f32 %0, %1, %2" : "=v"(r) : "v"(a), "v"(b));
  return r;
}

// slot k = [k4 k3 | k2 k1 k0] -> logical chi = 16*k2 + 4*(k4k3) + (k1k0)
__device__ __forceinline__ int qmap(int k) {
  return (((k >> 2) & 1) << 4) | (((k >> 3) & 3) << 2) | (k & 3);
}

// pack: element idx = ((p*4 + f)*64 + l)*8 + t   (chunk = 16B = 8 bf16)
// f = m*2 + h ; l = g*16 + col ; value = bf16(cores[p][qmap(8g+t)][m][h*16+col] - delta)
__global__ void pack_E(const float* __restrict__ cores, unsigned short* __restrict__ Ep) {
  int idx = blockIdx.x * 256 + threadIdx.x;
  if (idx >= (NSITES - 1) * 2048) return;
  int t = idx & 7;
  int l = (idx >> 3) & 63;
  int f = (idx >> 9) & 3;
  int p = idx >> 11;
  int g = l >> 4, col = l & 15;
  int m = f >> 1, h = f & 1;
  int k = 8 * g + t, c = h * 16 + col;
  int b = qmap(k);
  float val = cores[((p * 32 + b) * 2 + m) * 32 + c] - ((b == c) ? 1.0f : 0.0f);
  __hip_bfloat16 hv = __float2bfloat16(val);
  Ep[idx] = *(unsigned short*)&hv;
}

__device__ __forceinline__ void gll16(const void* g, void* l) {
  __builtin_amdgcn_global_load_lds(
      (const __attribute__((address_space(1))) unsigned*)g,
      (__attribute__((address_space(3))) unsigned*)l, 16, 0, 0);
}

// one chain step: consume panel (bufp,k_) and X(s_); v[NJ][8] fp32 state
#define STEPK(bufp, k_, s_)                                                     \
  {                                                                             \
    const short8* ep = (const short8*)&Elds[bufp][(k_)*4096 + lane * 16];       \
    const short8 A0 = ep[0], A1 = ep[64], A2 = ep[128], A3 = ep[192];           \
    _Pragma("unroll") for (int jj = 0; jj < NJ; ++jj) {                         \
      const float2 xj =                                                         \
          *(const float2*)(Xl + 2 * ((size_t)(s_)*BATCH + jj * 16));            \
      union { short8 s8; unsigned u[4]; } vb;                                   \
      vb.u[0] = cvt_pk_bf16(v[jj][0], v[jj][1]);                                \
      vb.u[1] = cvt_pk_bf16(v[jj][2], v[jj][3]);                                \
      vb.u[2] = cvt_pk_bf16(v[jj][4], v[jj][5]);                                \
      vb.u[3] = cvt_pk_bf16(v[jj][6], v[jj][7]);                                \
      const f32x4 z = {0.f, 0.f, 0.f, 0.f};                                     \
      f32x4 r0lo = __builtin_amdgcn_mfma_f32_16x16x32_bf16(A0, vb.s8, z, 0, 0, 0); \
      f32x4 r0hi = __builtin_amdgcn_mfma_f32_16x16x32_bf16(A1, vb.s8, z, 0, 0, 0); \
      f32x4 r1lo = __builtin_amdgcn_mfma_f32_16x16x32_bf16(A2, vb.s8, z, 0, 0, 0); \
      f32x4 r1hi = __builtin_amdgcn_mfma_f32_16x16x32_bf16(A3, vb.s8, z, 0, 0, 0); \
      const float x0s = xj.x, x1s = xj.y, sss = x0s + x1s;                      \
      _Pragma("unroll") for (int t = 0; t < 4; ++t) {                           \
        v[jj][t] = sss * v[jj][t] + x0s * r0lo[t] + x1s * r1lo[t];              \
        v[jj][4 + t] = sss * v[jj][4 + t] + x0s * r0hi[t] + x1s * r1hi[t];      \
      }                                                                         \
    }                                                                           \
  }

__global__ __launch_bounds__(256, 4) void mps_chain_kernel(
    const float* __restrict__ X, const float* __restrict__ core0,
    const float* __restrict__ coreN, const unsigned short* __restrict__ Ep,
    float* __restrict__ out) {
  __shared__ __align__(16) char Elds[2][SS * 4096];  // 32 KB
  const int tid = threadIdx.x;
  const int lane = tid & 63;
  const int wave = tid >> 6;
  const int col = lane & 15;  // batch column within 16-wide tile
  const int g = lane >> 4;    // k-group (slots 8g..8g+7)
  const int abase = blockIdx.x * BLOCK_BATCH + wave * (16 * NJ);
  const char* Epc = (const char*)Ep;
  const float* Xl = X + 2 * (size_t)(abase + col);

  // ---- prologue: stage panels p=0..3 (steps 1..4) into buf0; compute v0 ----
#pragma unroll
  for (int k = 0; k < SS; ++k)
    gll16(Epc + (size_t)k * 4096 + (size_t)tid * 16,
          &Elds[0][k * 4096 + wave * 1024]);

  float c0[2][8];
#pragma unroll
  for (int m = 0; m < 2; ++m)
#pragma unroll
    for (int t = 0; t < 8; ++t) c0[m][t] = core0[m * 32 + qmap(8 * g + t)];

  float v[NJ][8];
#pragma unroll
  for (int jj = 0; jj < NJ; ++jj) {
    const float2 xj = *(const float2*)(Xl + 2 * (size_t)(jj * 16));
#pragma unroll
    for (int t = 0; t < 8; ++t) v[jj][t] = xj.x * c0[0][t] + xj.y * c0[1][t];
  }
  __syncthreads();  // drains the 4 panel DMAs

  // ---- main chain: 15 supersteps x 4 steps, one barrier each ----
#pragma unroll 1
  for (int b = 0; b < 15; ++b) {
    const int buf = b & 1;
    const int pn = 4 * (b + 1);  // panels for next superstep
#pragma unroll
    for (int k = 0; k < SS; ++k)
      if (pn + k < NSITES - 1)
        gll16(Epc + (size_t)(pn + k) * 4096 + (size_t)tid * 16,
              &Elds[buf ^ 1][k * 4096 + wave * 1024]);

    const int s0 = 1 + 4 * b;
    STEPK(buf, 0, s0 + 0);
    STEPK(buf, 1, s0 + 1);
    STEPK(buf, 2, s0 + 2);
    STEPK(buf, 3, s0 + 3);
    __syncthreads();
  }

  // ---- tail: steps 61,62,63 from buf1 panels 0..2 ----
  STEPK(1, 0, 61);
  STEPK(1, 1, 62);
  STEPK(1, 2, 63);

  // ---- epilogue: out = |v @ coreN| ----
  float cN[8][2];
#pragma unroll
  for (int t = 0; t < 8; ++t) {
    cN[t][0] = coreN[qmap(8 * g + t) * 2 + 0];
    cN[t][1] = coreN[qmap(8 * g + t) * 2 + 1];
  }
#pragma unroll
  for (int jj = 0; jj < NJ; ++jj) {
    float p0 = 0.f, p1 = 0.f;
#pragma unroll
    for (int t = 0; t < 8; ++t) {
      p0 += v[jj][t] * cN[t][0];
      p1 += v[jj][t] * cN[t][1];
    }
    p0 += __shfl_xor(p0, 16);
    p0 += __shfl_xor(p0, 32);
    p1 += __shfl_xor(p1, 16);
    p1 += __shfl_xor(p1, 32);
    if (g == 0) {
      const int a = abase + jj * 16 + col;
      out[2 * a] = fabsf(p0);
      out[2 * a + 1] = fabsf(p1);
    }
  }
}

extern "C" void kernel_launch(void* const* d_in, const int* in_sizes, int n_in,
                              void* d_out, int out_size, void* d_ws, size_t ws_size,
                              hipStream_t stream) {
  const float* X = (const float*)d_in[0];
  const float* core0 = (const float*)d_in[1];
  const float* cores = (const float*)d_in[2];
  const float* coreN = (const float*)d_in[3];
  float* out = (float*)d_out;
  unsigned short* Ep = (unsigned short*)d_ws;  // 258048 bytes

  hipLaunchKernelGGL(pack_E, dim3(((NSITES - 1) * 2048 + 255) / 256), dim3(256), 0, stream,
                     cores, Ep);
  hipLaunchKernelGGL(mps_chain_kernel, dim3(BATCH / BLOCK_BATCH), dim3(256), 0, stream, X,
                     core0, coreN, Ep, out);
}

// Round 11
// 102.951 us; speedup vs baseline: 1.2341x; 1.2341x over previous
//
#include <hip/hip_runtime.h>
#include <hip/hip_bf16.h>

#define BATCH 262144
#define NSITES 64
#define NJ 4                    // j-tiles per wave (64 batch elems/wave)
#define BLOCK_BATCH 256         // batch elems per 256-thread block

typedef __attribute__((ext_vector_type(8))) short short8;
typedef __attribute__((ext_vector_type(4))) float f32x4;

__device__ __forceinline__ unsigned cvt_pk_bf16(float a, float b) {
  unsigned r;
  asm("v_cvt_pk_bf16_f32 %0, %1, %2" : "=v"(r) : "v"(a), "v"(b));
  return r;
}

// slot k = [k4 k3 | k2 k1 k0] -> logical chi = 16*k2 + 4*(k4k3) + (k1k0)
__device__ __forceinline__ int qmap(int k) {
  return (((k >> 2) & 1) << 4) | (((k >> 3) & 3) << 2) | (k & 3);
}

// pack: element idx = ((p*4 + f)*64 + l)*8 + t   (chunk = 16B = 8 bf16)
// f = m*2 + h ; l = g*16 + col ; value = bf16(cores[p][qmap(8g+t)][m][h*16+col] - delta)
__global__ void pack_E(const float* __restrict__ cores, unsigned short* __restrict__ Ep) {
  int idx = blockIdx.x * 256 + threadIdx.x;
  if (idx >= (NSITES - 1) * 2048) return;
  int t = idx & 7;
  int l = (idx >> 3) & 63;
  int f = (idx >> 9) & 3;
  int p = idx >> 11;
  int g = l >> 4, col = l & 15;
  int m = f >> 1, h = f & 1;
  int k = 8 * g + t, c = h * 16 + col;
  int b = qmap(k);
  float val = cores[((p * 32 + b) * 2 + m) * 32 + c] - ((b == c) ? 1.0f : 0.0f);
  __hip_bfloat16 hv = __float2bfloat16(val);
  Ep[idx] = *(unsigned short*)&hv;
}

__device__ __forceinline__ void gll16(const void* g, void* l) {
  __builtin_amdgcn_global_load_lds(
      (const __attribute__((address_space(1))) unsigned*)g,
      (__attribute__((address_space(3))) unsigned*)l, 16, 0, 0);
}

#define BODYJ(jj, xx0, xx1)                                                     \
  {                                                                             \
    union { short8 s8; unsigned u[4]; } vb;                                     \
    vb.u[0] = cvt_pk_bf16(v[jj][0], v[jj][1]);                                  \
    vb.u[1] = cvt_pk_bf16(v[jj][2], v[jj][3]);                                  \
    vb.u[2] = cvt_pk_bf16(v[jj][4], v[jj][5]);                                  \
    vb.u[3] = cvt_pk_bf16(v[jj][6], v[jj][7]);                                  \
    const f32x4 z = {0.f, 0.f, 0.f, 0.f};                                       \
    f32x4 r0lo = __builtin_amdgcn_mfma_f32_16x16x32_bf16(A0, vb.s8, z, 0, 0, 0); \
    f32x4 r0hi = __builtin_amdgcn_mfma_f32_16x16x32_bf16(A1, vb.s8, z, 0, 0, 0); \
    f32x4 r1lo = __builtin_amdgcn_mfma_f32_16x16x32_bf16(A2, vb.s8, z, 0, 0, 0); \
    f32x4 r1hi = __builtin_amdgcn_mfma_f32_16x16x32_bf16(A3, vb.s8, z, 0, 0, 0); \
    const float ss = (xx0) + (xx1);                                             \
    _Pragma("unroll") for (int t = 0; t < 4; ++t) {                             \
      v[jj][t] = ss * v[jj][t] + (xx0)*r0lo[t] + (xx1)*r1lo[t];                 \
      v[jj][4 + t] = ss * v[jj][4 + t] + (xx0)*r0hi[t] + (xx1)*r1hi[t];         \
    }                                                                           \
  }

__global__ __launch_bounds__(256, 4) void mps_chain_kernel(
    const float* __restrict__ X, const float* __restrict__ core0,
    const float* __restrict__ coreN, const unsigned short* __restrict__ Ep,
    float* __restrict__ out) {
  // 4-slot ring: pair s lives in slot s&3. E = 4KB panel, X = 2KB panel.
  __shared__ __align__(16) char Elds[4][4096];
  __shared__ __align__(16) char Xlds[4][2048];
  const int tid = threadIdx.x;
  const int lane = tid & 63;
  const int wave = tid >> 6;
  const int col = lane & 15;  // batch column within 16-wide tile
  const int g = lane >> 4;    // k-group (slots 8g..8g+7)
  const int abase = blockIdx.x * BLOCK_BATCH + wave * (16 * NJ);
  const char* Epc = (const char*)Ep;
  const char* Xc = (const char*)X;
  const size_t xblock = (size_t)blockIdx.x * (BLOCK_BATCH * 8);

  // ---- v0 = X[0] @ core0 (plain compiler loads, one-time) ----
  float c0[2][8];
#pragma unroll
  for (int m = 0; m < 2; ++m)
#pragma unroll
    for (int t = 0; t < 8; ++t) c0[m][t] = core0[m * 32 + qmap(8 * g + t)];

  float v[NJ][8];
#pragma unroll
  for (int jj = 0; jj < NJ; ++jj) {
    const float2 xj =
        *(const float2*)(X + 2 * (size_t)(abase + jj * 16 + col));
#pragma unroll
    for (int t = 0; t < 8; ++t) v[jj][t] = xj.x * c0[0][t] + xj.y * c0[1][t];
  }

  // ---- prologue: stage pairs 1..3 into slots 1..3 (order: E,X per pair) ----
#pragma unroll
  for (int k = 1; k <= 3; ++k) {
    gll16(Epc + (size_t)(k - 1) * 4096 + (size_t)tid * 16,
          &Elds[k][wave * 1024]);
    if (lane < 32)
      gll16(Xc + (size_t)k * (BATCH * 8) + xblock + wave * 512 + lane * 16,
            &Xlds[k][wave * 512]);
  }
  asm volatile("s_waitcnt vmcnt(4)" ::: "memory");  // pair 1 complete
  __builtin_amdgcn_s_barrier();                     // ... in all waves

  // ---- main chain: counted-vmcnt pipeline, distance 3, never vmcnt(0) ----
  // Invariant entering step s: <=4 outstanding = pairs {s+1, s+2}.
#pragma unroll 1
  for (int s = 1; s < NSITES; ++s) {
    const int rs = s & 3;
    const int ws = (s + 3) & 3;
    const int pk = (s + 3 < NSITES) ? s + 3 : NSITES - 1;  // clamped refetch is benign
    gll16(Epc + (size_t)(pk - 1) * 4096 + (size_t)tid * 16,
          &Elds[ws][wave * 1024]);
    if (lane < 32)
      gll16(Xc + (size_t)pk * (BATCH * 8) + xblock + wave * 512 + lane * 16,
            &Xlds[ws][wave * 512]);
    // 6 in flight -> wait to 4: completes pair s+1 (staged 2 steps ago).
    asm volatile("s_waitcnt vmcnt(4)" ::: "memory");

    const short8* ep = (const short8*)&Elds[rs][lane * 16];
    const short8 A0 = ep[0], A1 = ep[64], A2 = ep[128], A3 = ep[192];
    const float* xp = (const float*)&Xlds[rs][wave * 512 + col * 8];
    const float x00 = xp[0],  x01 = xp[1];
    const float x10 = xp[32], x11 = xp[33];
    const float x20 = xp[64], x21 = xp[65];
    const float x30 = xp[96], x31 = xp[97];

    BODYJ(0, x00, x01);
    BODYJ(1, x10, x11);
    BODYJ(2, x20, x21);
    BODYJ(3, x30, x31);

    // end-of-step barrier: publishes pair s+1 completion to all waves and
    // protects slot (s+4)&3 == rs from next step's DMA until reads are done.
    __builtin_amdgcn_s_barrier();
  }

  // ---- epilogue: out = |v @ coreN| ----
  float cN[8][2];
#pragma unroll
  for (int t = 0; t < 8; ++t) {
    cN[t][0] = coreN[qmap(8 * g + t) * 2 + 0];
    cN[t][1] = coreN[qmap(8 * g + t) * 2 + 1];
  }
#pragma unroll
  for (int jj = 0; jj < NJ; ++jj) {
    float p0 = 0.f, p1 = 0.f;
#pragma unroll
    for (int t = 0; t < 8; ++t) {
      p0 += v[jj][t] * cN[t][0];
      p1 += v[jj][t] * cN[t][1];
    }
    p0 += __shfl_xor(p0, 16);
    p0 += __shfl_xor(p0, 32);
    p1 += __shfl_xor(p1, 16);
    p1 += __shfl_xor(p1, 32);
    if (g == 0) {
      const int a = abase + jj * 16 + col;
      out[2 * a] = fabsf(p0);
      out[2 * a + 1] = fabsf(p1);
    }
  }
}

extern "C" void kernel_launch(void* const* d_in, const int* in_sizes, int n_in,
                              void* d_out, int out_size, void* d_ws, size_t ws_size,
                              hipStream_t stream) {
  const float* X = (const float*)d_in[0];
  const float* core0 = (const float*)d_in[1];
  const float* cores = (const float*)d_in[2];
  const float* coreN = (const float*)d_in[3];
  float* out = (float*)d_out;
  unsigned short* Ep = (unsigned short*)d_ws;  // 258048 bytes

  hipLaunchKernelGGL(pack_E, dim3(((NSITES - 1) * 2048 + 255) / 256), dim3(256), 0, stream,
                     cores, Ep);
  hipLaunchKernelGGL(mps_chain_kernel, dim3(BATCH / BLOCK_BATCH), dim3(256), 0, stream, X,
                     core0, coreN, Ep, out);
}